// Round 1
// baseline (1177.779 us; speedup 1.0000x reference)
//
#include <hip/hip_runtime.h>
#include <stdint.h>

typedef __attribute__((ext_vector_type(8))) short short8;
typedef __attribute__((ext_vector_type(4))) float f32x4;

#define NN 1024
#define NBATCH 16384

__device__ __forceinline__ unsigned short f32_to_bf16_rne(float f) {
  unsigned int u = __float_as_uint(f);
  unsigned int r = (u + 0x7fffu + ((u >> 16) & 1u)) >> 16;
  return (unsigned short)r;
}

__device__ __forceinline__ unsigned int pack2bf(float lo, float hi) {
  return (unsigned int)f32_to_bf16_rne(lo) | ((unsigned int)f32_to_bf16_rne(hi) << 16);
}

// -------------------- prep: tau = 2/(u.u), sigmas --------------------
__global__ __launch_bounds__(256) void prep_kernel(
    const float* __restrict__ U, const float* __restrict__ V,
    const float* __restrict__ p, float* __restrict__ tau_u,
    float* __restrict__ tau_v, float* __restrict__ sigmas) {
  int wave = threadIdx.x >> 6, lane = threadIdx.x & 63;
  int row = blockIdx.x * 4 + wave;
  if (row < 2048) {
    const float* u = (row < NN) ? (U + (size_t)row * NN) : (V + (size_t)(row - NN) * NN);
    float s = 0.f;
#pragma unroll
    for (int t = 0; t < 16; ++t) { float a = u[lane + (t << 6)]; s += a * a; }
#pragma unroll
    for (int off = 1; off < 64; off <<= 1) s += __shfl_xor(s, off);
    if (lane == 0) {
      float tau = 2.0f / s;
      if (row < NN) tau_u[row] = tau;
      else tau_v[row - NN] = tau;
    }
  } else if (row < 2064) {
    int j = ((row - 2048) << 6) + lane;
    float pj = p[j];
    float sg = 1.0f / (1.0f + expf(-pj));
    // 2*r*(sigmoid(p)-0.5) + sigma_mean ; r=0.45, mean=0.55
    sigmas[j] = 0.9f * (sg - 0.5f) + 0.55f;
  }
}

// -------------------- build M^T (bf16): one M-row per wave --------------------
// Row r of M evolves independently: v = e_r; v -= tau*(v.u)*u over U rows 0..1023,
// then v *= sigma, then V rows 1023..0. Lane layout: v[t] holds element lane+64t.
__global__ __launch_bounds__(256) void build_m_kernel(
    const float* __restrict__ U, const float* __restrict__ V,
    const float* __restrict__ tau_u, const float* __restrict__ tau_v,
    const float* __restrict__ sigmas, unsigned short* __restrict__ Mt) {
  __shared__ float ubuf[2][NN];
  const int tid = threadIdx.x;
  const int wave = tid >> 6, lane = tid & 63;
  const int row = (blockIdx.x << 2) + wave;

  float v[16];
#pragma unroll
  for (int t = 0; t < 16; ++t) v[t] = (lane + (t << 6) == row) ? 1.0f : 0.0f;

  // pre-stage u_0 (full row)
  *reinterpret_cast<float4*>(&ubuf[0][tid << 2]) =
      *reinterpret_cast<const float4*>(U + (tid << 2));
  __syncthreads();

  int pb = 0;

  // ---- U phase: i = 0..1023 ----
  for (int i = 0; i < NN; ++i) {
    // prefetch next reflector row (U row i+1, or V row 1023 at the seam)
    const float* nsrc;
    int nq0;
    if (i + 1 < NN) { nsrc = U + (size_t)(i + 1) * NN; nq0 = (i + 1) >> 8; }
    else            { nsrc = V + (size_t)(NN - 1) * NN; nq0 = (NN - 1) >> 8; }
    bool ld = (tid >> 6) >= nq0;  // stage only j >= 256*nq0 (support of u)
    float4 g;
    if (ld) g = *reinterpret_cast<const float4*>(nsrc + (tid << 2));

    const int q0 = i >> 8;  // active quarter-blocks: q >= q0
    float ureg[16];
    float dot = 0.f;
#pragma unroll
    for (int q = 0; q < 4; ++q) {
      if (q >= q0) {
#pragma unroll
        for (int tt = 0; tt < 4; ++tt) {
          int t = (q << 2) + tt;
          ureg[t] = ubuf[pb][lane + (t << 6)];
          dot += ureg[t] * v[t];
        }
      }
    }
#pragma unroll
    for (int off = 1; off < 64; off <<= 1) dot += __shfl_xor(dot, off);
    const float alpha = dot * tau_u[i];
#pragma unroll
    for (int q = 0; q < 4; ++q) {
      if (q >= q0) {
#pragma unroll
        for (int tt = 0; tt < 4; ++tt) {
          int t = (q << 2) + tt;
          v[t] -= alpha * ureg[t];
        }
      }
    }
    if (ld) *reinterpret_cast<float4*>(&ubuf[pb ^ 1][tid << 2]) = g;
    __syncthreads();
    pb ^= 1;
  }

  // ---- sigma scaling ----
#pragma unroll
  for (int t = 0; t < 16; ++t) v[t] *= sigmas[lane + (t << 6)];

  // ---- V phase: i = 1023..0 ----
  for (int i = NN - 1; i >= 0; --i) {
    int nq0 = (i > 0) ? ((i - 1) >> 8) : 0;
    const float* nsrc = V + (size_t)((i > 0) ? (i - 1) : 0) * NN;
    bool ld = (i > 0) && ((tid >> 6) >= nq0);
    float4 g;
    if (ld) g = *reinterpret_cast<const float4*>(nsrc + (tid << 2));

    const int q0 = i >> 8;
    float ureg[16];
    float dot = 0.f;
#pragma unroll
    for (int q = 0; q < 4; ++q) {
      if (q >= q0) {
#pragma unroll
        for (int tt = 0; tt < 4; ++tt) {
          int t = (q << 2) + tt;
          ureg[t] = ubuf[pb][lane + (t << 6)];
          dot += ureg[t] * v[t];
        }
      }
    }
#pragma unroll
    for (int off = 1; off < 64; off <<= 1) dot += __shfl_xor(dot, off);
    const float alpha = dot * tau_v[i];
#pragma unroll
    for (int q = 0; q < 4; ++q) {
      if (q >= q0) {
#pragma unroll
        for (int tt = 0; tt < 4; ++tt) {
          int t = (q << 2) + tt;
          v[t] -= alpha * ureg[t];
        }
      }
    }
    if (ld) *reinterpret_cast<float4*>(&ubuf[pb ^ 1][tid << 2]) = g;
    __syncthreads();
    pb ^= 1;
  }

  // ---- store Mt[c][k] = M[k][c], i.e. Mt[j][row] = v_j ----
#pragma unroll
  for (int t = 0; t < 16; ++t) {
    Mt[(size_t)(lane + (t << 6)) * NN + row] = f32_to_bf16_rne(v[t]);
  }
}

// -------------------- GEMM: out = x @ M + bias (A f32->bf16 on the fly) --------------------
#define BM 128
#define BN 128
#define BK 32
#define LDK 40  // padded LDS stride (bf16 elems) -> spreads bank groups

__global__ __launch_bounds__(256) void gemm_kernel(
    const float* __restrict__ X, const unsigned short* __restrict__ Mt,
    const float* __restrict__ bias, float* __restrict__ Out) {
  __shared__ unsigned short As[BM * LDK];
  __shared__ unsigned short Bs[BN * LDK];
  const int tid = threadIdx.x;
  const int lane = tid & 63, wave = tid >> 6;
  const int bm = blockIdx.x & 127;  // 128 m-tiles (consecutive bids share n-tile -> L3 reuse)
  const int bn = blockIdx.x >> 7;   // 8 n-tiles
  const int m0 = bm * BM, n0 = bn * BN;
  const int wm = wave & 1, wn = wave >> 1;  // 2x2 waves, 64x64 each

  const int srow = tid >> 1;         // staging row 0..127 (same for A and B tiles)
  const int scol = (tid & 1) << 4;   // 0 or 16
  const float* aptr = X + (size_t)(m0 + srow) * NN + scol;
  const unsigned short* bptr = Mt + (size_t)(n0 + srow) * NN + scol;

  f32x4 acc[4][4];
#pragma unroll
  for (int a = 0; a < 4; ++a)
#pragma unroll
    for (int b = 0; b < 4; ++b) acc[a][b] = 0.f;

  // prologue: load k-tile 0 into regs
  float4 ra0 = *reinterpret_cast<const float4*>(aptr + 0);
  float4 ra1 = *reinterpret_cast<const float4*>(aptr + 4);
  float4 ra2 = *reinterpret_cast<const float4*>(aptr + 8);
  float4 ra3 = *reinterpret_cast<const float4*>(aptr + 12);
  uint4 rb0 = *reinterpret_cast<const uint4*>(bptr + 0);
  uint4 rb1 = *reinterpret_cast<const uint4*>(bptr + 8);

  const int arow0 = wm * 64;
  const int brow0 = wn * 64;
  const int fr = lane & 15;
  const int kb = (lane >> 4) << 3;  // k-group base: 0,8,16,24

#pragma unroll 1
  for (int kt = 0; kt < NN / BK; ++kt) {
    __syncthreads();  // previous tile fully consumed
    // stage current regs -> LDS (convert A to bf16)
    uint4 w0, w1;
    w0.x = pack2bf(ra0.x, ra0.y); w0.y = pack2bf(ra0.z, ra0.w);
    w0.z = pack2bf(ra1.x, ra1.y); w0.w = pack2bf(ra1.z, ra1.w);
    w1.x = pack2bf(ra2.x, ra2.y); w1.y = pack2bf(ra2.z, ra2.w);
    w1.z = pack2bf(ra3.x, ra3.y); w1.w = pack2bf(ra3.z, ra3.w);
    *reinterpret_cast<uint4*>(&As[srow * LDK + scol]) = w0;
    *reinterpret_cast<uint4*>(&As[srow * LDK + scol + 8]) = w1;
    *reinterpret_cast<uint4*>(&Bs[srow * LDK + scol]) = rb0;
    *reinterpret_cast<uint4*>(&Bs[srow * LDK + scol + 8]) = rb1;
    __syncthreads();
    // prefetch next tile while computing this one
    if (kt + 1 < NN / BK) {
      const float* ap = aptr + (kt + 1) * BK;
      const unsigned short* bp = bptr + (kt + 1) * BK;
      ra0 = *reinterpret_cast<const float4*>(ap + 0);
      ra1 = *reinterpret_cast<const float4*>(ap + 4);
      ra2 = *reinterpret_cast<const float4*>(ap + 8);
      ra3 = *reinterpret_cast<const float4*>(ap + 12);
      rb0 = *reinterpret_cast<const uint4*>(bp + 0);
      rb1 = *reinterpret_cast<const uint4*>(bp + 8);
    }
    // fragments + 16 MFMAs
    short8 af[4], bf[4];
#pragma unroll
    for (int tr = 0; tr < 4; ++tr)
      af[tr] = *reinterpret_cast<const short8*>(&As[(arow0 + tr * 16 + fr) * LDK + kb]);
#pragma unroll
    for (int tc = 0; tc < 4; ++tc)
      bf[tc] = *reinterpret_cast<const short8*>(&Bs[(brow0 + tc * 16 + fr) * LDK + kb]);
#pragma unroll
    for (int tr = 0; tr < 4; ++tr)
#pragma unroll
      for (int tc = 0; tc < 4; ++tc)
        acc[tr][tc] = __builtin_amdgcn_mfma_f32_16x16x32_bf16(af[tr], bf[tc], acc[tr][tc], 0, 0, 0);
  }

  // epilogue: C/D layout col=lane&15, row=(lane>>4)*4+q
  const int rq = (lane >> 4) << 2;
#pragma unroll
  for (int tc = 0; tc < 4; ++tc) {
    const int gc = n0 + brow0 + tc * 16 + fr;
    const float bv = bias[gc];
#pragma unroll
    for (int tr = 0; tr < 4; ++tr) {
      const int gr = m0 + arow0 + tr * 16 + rq;
#pragma unroll
      for (int q = 0; q < 4; ++q) {
        Out[(size_t)(gr + q) * NN + gc] = acc[tr][tc][q] + bv;
      }
    }
  }
}

extern "C" void kernel_launch(void* const* d_in, const int* in_sizes, int n_in,
                              void* d_out, int out_size, void* d_ws, size_t ws_size,
                              hipStream_t stream) {
  const float* x = (const float*)d_in[0];
  const float* U = (const float*)d_in[1];
  const float* V = (const float*)d_in[2];
  const float* p = (const float*)d_in[3];
  const float* bias = (const float*)d_in[4];
  float* out = (float*)d_out;

  char* ws = (char*)d_ws;
  float* tau_u = (float*)(ws);
  float* tau_v = (float*)(ws + 4096);
  float* sigmas = (float*)(ws + 8192);
  unsigned short* Mt = (unsigned short*)(ws + 16384);  // [1024][1024] bf16 = 2 MB

  prep_kernel<<<516, 256, 0, stream>>>(U, V, p, tau_u, tau_v, sigmas);
  build_m_kernel<<<256, 256, 0, stream>>>(U, V, tau_u, tau_v, sigmas, Mt);
  gemm_kernel<<<1024, 256, 0, stream>>>(x, Mt, bias, out);
}

// Round 2
// 547.877 us; speedup vs baseline: 2.1497x; 2.1497x over previous
//
#include <hip/hip_runtime.h>
#include <stdint.h>

typedef __attribute__((ext_vector_type(8))) short short8;
typedef __attribute__((ext_vector_type(4))) float f32x4;

#define NN 1024
#define NBATCH 16384

__device__ __forceinline__ unsigned short f32_to_bf16_rne(float f) {
  unsigned int u = __float_as_uint(f);
  unsigned int r = (u + 0x7fffu + ((u >> 16) & 1u)) >> 16;
  return (unsigned short)r;
}

__device__ __forceinline__ unsigned int pack2bf(float lo, float hi) {
  return (unsigned int)f32_to_bf16_rne(lo) | ((unsigned int)f32_to_bf16_rne(hi) << 16);
}

// -------------------- prep: tau = 2/(u.u), sigmas --------------------
__global__ __launch_bounds__(256) void prep_kernel(
    const float* __restrict__ U, const float* __restrict__ V,
    const float* __restrict__ p, float* __restrict__ tau_u,
    float* __restrict__ tau_v, float* __restrict__ sigmas) {
  int wave = threadIdx.x >> 6, lane = threadIdx.x & 63;
  int row = blockIdx.x * 4 + wave;
  if (row < 2048) {
    const float* u = (row < NN) ? (U + (size_t)row * NN) : (V + (size_t)(row - NN) * NN);
    float s = 0.f;
#pragma unroll
    for (int t = 0; t < 16; ++t) { float a = u[lane + (t << 6)]; s += a * a; }
#pragma unroll
    for (int off = 1; off < 64; off <<= 1) s += __shfl_xor(s, off);
    if (lane == 0) {
      float tau = 2.0f / s;
      if (row < NN) tau_u[row] = tau;
      else tau_v[row - NN] = tau;
    }
  } else if (row < 2064) {
    int j = ((row - 2048) << 6) + lane;
    float pj = p[j];
    float sg = 1.0f / (1.0f + expf(-pj));
    sigmas[j] = 0.9f * (sg - 0.5f) + 0.55f;  // r=0.45, mean=0.55
  }
}

// -------------------- gram + T8 per block of 8 reflectors --------------------
// Block index blk 0..255: blk<128 -> U bank, application order rows 8*blk+j (j=0..7).
// blk>=128 -> V bank, s=blk-128, application order rows 1023-8s-j (j=0..7).
// T recurrence (compact WY): T[j][j]=tau_j; T[i][j] = -tau_j * sum_{k=i..j-1} T[i][k]*G[k][j],
// where G[k][j] = u_k . u_j (application-order indices).
__global__ __launch_bounds__(64) void gram_t8_kernel(
    const float* __restrict__ U, const float* __restrict__ V,
    const float* __restrict__ tau_u, const float* __restrict__ tau_v,
    float* __restrict__ T8all) {
  __shared__ float G[64];
  const int blk = blockIdx.x;
  const int lane = threadIdx.x;
  const float* bank;
  int rbase, rsign, st;
  if (blk < 128) { bank = U; rbase = 8 * blk; rsign = 1; st = 8 * blk; }
  else { int s = blk - 128; bank = V; rbase = 1023 - 8 * s; rsign = -1; st = 1016 - 8 * s; }

  if (lane < 28) {
    int j = 1, k = 0, t = lane;
    for (int jj = 1; jj < 8; ++jj) {
      int lo = jj * (jj - 1) / 2, hi = jj * (jj + 1) / 2;
      if (t >= lo && t < hi) { j = jj; k = t - lo; }
    }
    const float* rk = bank + (size_t)(rbase + rsign * k) * NN;
    const float* rj = bank + (size_t)(rbase + rsign * j) * NN;
    float acc = 0.f;
    for (int i = st >> 2; i < 256; ++i) {
      float4 a = *reinterpret_cast<const float4*>(rk + 4 * i);
      float4 b = *reinterpret_cast<const float4*>(rj + 4 * i);
      acc += a.x * b.x + a.y * b.y + a.z * b.z + a.w * b.w;
    }
    G[k * 8 + j] = acc;
  }
  __syncthreads();

  if (lane < 8) {
    float Tr[8];
#pragma unroll
    for (int j = 0; j < 8; ++j) Tr[j] = 0.f;
#pragma unroll
    for (int j = 0; j < 8; ++j) {
      int grow = rbase + rsign * j;
      float tj = (blk < 128) ? tau_u[grow] : tau_v[grow];
      float a = 0.f;
#pragma unroll
      for (int k = 0; k < 8; ++k) {
        if (k < j) a += Tr[k] * G[k * 8 + j];
      }
      Tr[j] = (lane == j) ? tj : (-tj * a);  // lanes > j: a==0 -> 0
    }
#pragma unroll
    for (int j = 0; j < 8; ++j) T8all[(size_t)blk * 64 + lane * 8 + j] = Tr[j];
  }
}

// -------------------- build M^T: one M-row per wave, 8-reflector WY blocks ----
// Element-to-lane map: v[4q+r] holds element e = 256*q + 4*lane + r (bijection).
__device__ __forceinline__ void stage_block(int step, float* lbuf, float* tbuf,
    const float* __restrict__ U, const float* __restrict__ V,
    const float* __restrict__ T8all, int wave, int lane) {
  if (step >= 256) return;
  int q0, rbase, rsign;
  const float* bank;
  if (step < 128) { q0 = step >> 5; bank = U; rbase = 8 * step; rsign = 1; }
  else { int s = step - 128; q0 = (1016 - 8 * s) >> 8; bank = V; rbase = 1023 - 8 * s; rsign = -1; }
#pragma unroll
  for (int c = 0; c < 8; ++c) {
    const int chunk = wave * 8 + c;
    const int slot = chunk >> 2, q = chunk & 3;
    if (q < q0) continue;
    const int grow = rbase + rsign * slot;
    const float* gsrc = bank + (size_t)grow * NN + q * 256 + lane * 4;
    float* ldst = lbuf + slot * NN + q * 256;
    __builtin_amdgcn_global_load_lds(
        (const __attribute__((address_space(1))) void*)gsrc,
        (__attribute__((address_space(3))) void*)ldst, 16, 0, 0);
  }
  if (wave == 0 && lane < 16) {
    float4 t = *reinterpret_cast<const float4*>(T8all + (size_t)step * 64 + lane * 4);
    *reinterpret_cast<float4*>(tbuf + lane * 4) = t;
  }
}

template <int Q0>
__device__ __forceinline__ void apply_block(const float* __restrict__ ub,
    const float* __restrict__ tb, float* __restrict__ v, int lane) {
  float uc[8][(4 - Q0) * 4];
  float c[8];
#pragma unroll
  for (int j = 0; j < 8; ++j) {
    float acc = 0.f;
#pragma unroll
    for (int q = Q0; q < 4; ++q) {
      const float4 uu = *reinterpret_cast<const float4*>(&ub[j * NN + q * 256 + lane * 4]);
      const int ci = (q - Q0) * 4;
      uc[j][ci + 0] = uu.x; uc[j][ci + 1] = uu.y;
      uc[j][ci + 2] = uu.z; uc[j][ci + 3] = uu.w;
      acc += uu.x * v[4 * q + 0] + uu.y * v[4 * q + 1] +
             uu.z * v[4 * q + 2] + uu.w * v[4 * q + 3];
    }
    c[j] = acc;
  }
#pragma unroll
  for (int off = 1; off < 64; off <<= 1) {
#pragma unroll
    for (int j = 0; j < 8; ++j) c[j] += __shfl_xor(c[j], off);
  }
  float w[8];
#pragma unroll
  for (int j = 0; j < 8; ++j) {
    float acc = 0.f;
#pragma unroll
    for (int k = 0; k < 8; ++k) {
      if (k <= j) acc += c[k] * tb[k * 8 + j];
    }
    w[j] = acc;
  }
#pragma unroll
  for (int q = Q0; q < 4; ++q) {
#pragma unroll
    for (int r = 0; r < 4; ++r) {
      float acc = v[4 * q + r];
#pragma unroll
      for (int j = 0; j < 8; ++j) acc -= w[j] * uc[j][(q - Q0) * 4 + r];
      v[4 * q + r] = acc;
    }
  }
}

__global__ __launch_bounds__(256, 1) void build_m2_kernel(
    const float* __restrict__ U, const float* __restrict__ V,
    const float* __restrict__ sigmas, const float* __restrict__ T8all,
    unsigned short* __restrict__ Mt) {
  __shared__ float ubuf[2][8 * NN];
  __shared__ float tbuf[2][64];
  const int tid = threadIdx.x;
  const int wave = tid >> 6, lane = tid & 63;
  const int row = (blockIdx.x << 2) + wave;

  float v[16];
#pragma unroll
  for (int q = 0; q < 4; ++q)
#pragma unroll
    for (int r = 0; r < 4; ++r)
      v[4 * q + r] = (256 * q + 4 * lane + r == row) ? 1.0f : 0.0f;

  stage_block(0, ubuf[0], tbuf[0], U, V, T8all, wave, lane);
  int pb = 0;

#define SEG(Q0C, BASE)                                                        \
  for (int s = 0; s < 32; ++s) {                                              \
    const int step = (BASE) + s;                                              \
    __syncthreads(); /* drains vmcnt: staged buf ready, prev buf consumed */  \
    stage_block(step + 1, ubuf[pb ^ 1], tbuf[pb ^ 1], U, V, T8all, wave, lane); \
    apply_block<Q0C>(ubuf[pb], tbuf[pb], v, lane);                            \
    pb ^= 1;                                                                  \
  }

  // U phase: q0 = step>>5
  SEG(0, 0) SEG(1, 32) SEG(2, 64) SEG(3, 96)

  // sigma
#pragma unroll
  for (int q = 0; q < 4; ++q) {
    float4 sg = *reinterpret_cast<const float4*>(&sigmas[256 * q + 4 * lane]);
    v[4 * q + 0] *= sg.x; v[4 * q + 1] *= sg.y;
    v[4 * q + 2] *= sg.z; v[4 * q + 3] *= sg.w;
  }

  // V phase: steps 128..255, q0 = (1016-8s)>>8 descends 3,2,1,0 in 32-step segs
  SEG(3, 128) SEG(2, 160) SEG(1, 192) SEG(0, 224)
#undef SEG

  // pack: Mt[e][row] = bf16(v), e = 256q + 4lane + r
#pragma unroll
  for (int q = 0; q < 4; ++q)
#pragma unroll
    for (int r = 0; r < 4; ++r)
      Mt[(size_t)(256 * q + 4 * lane + r) * NN + row] = f32_to_bf16_rne(v[4 * q + r]);
}

// -------------------- GEMM: out = x @ M + bias (A f32->bf16 on the fly) --------------------
#define BM 128
#define BN 128
#define BK 32
#define LDK 40

__global__ __launch_bounds__(256) void gemm_kernel(
    const float* __restrict__ X, const unsigned short* __restrict__ Mt,
    const float* __restrict__ bias, float* __restrict__ Out) {
  __shared__ unsigned short As[BM * LDK];
  __shared__ unsigned short Bs[BN * LDK];
  const int tid = threadIdx.x;
  const int lane = tid & 63, wave = tid >> 6;
  const int bm = blockIdx.x & 127;
  const int bn = blockIdx.x >> 7;
  const int m0 = bm * BM, n0 = bn * BN;
  const int wm = wave & 1, wn = wave >> 1;

  const int srow = tid >> 1;
  const int scol = (tid & 1) << 4;
  const float* aptr = X + (size_t)(m0 + srow) * NN + scol;
  const unsigned short* bptr = Mt + (size_t)(n0 + srow) * NN + scol;

  f32x4 acc[4][4];
#pragma unroll
  for (int a = 0; a < 4; ++a)
#pragma unroll
    for (int b = 0; b < 4; ++b) acc[a][b] = 0.f;

  float4 ra0 = *reinterpret_cast<const float4*>(aptr + 0);
  float4 ra1 = *reinterpret_cast<const float4*>(aptr + 4);
  float4 ra2 = *reinterpret_cast<const float4*>(aptr + 8);
  float4 ra3 = *reinterpret_cast<const float4*>(aptr + 12);
  uint4 rb0 = *reinterpret_cast<const uint4*>(bptr + 0);
  uint4 rb1 = *reinterpret_cast<const uint4*>(bptr + 8);

  const int arow0 = wm * 64;
  const int brow0 = wn * 64;
  const int fr = lane & 15;
  const int kb = (lane >> 4) << 3;

#pragma unroll 1
  for (int kt = 0; kt < NN / BK; ++kt) {
    __syncthreads();
    uint4 w0, w1;
    w0.x = pack2bf(ra0.x, ra0.y); w0.y = pack2bf(ra0.z, ra0.w);
    w0.z = pack2bf(ra1.x, ra1.y); w0.w = pack2bf(ra1.z, ra1.w);
    w1.x = pack2bf(ra2.x, ra2.y); w1.y = pack2bf(ra2.z, ra2.w);
    w1.z = pack2bf(ra3.x, ra3.y); w1.w = pack2bf(ra3.z, ra3.w);
    *reinterpret_cast<uint4*>(&As[srow * LDK + scol]) = w0;
    *reinterpret_cast<uint4*>(&As[srow * LDK + scol + 8]) = w1;
    *reinterpret_cast<uint4*>(&Bs[srow * LDK + scol]) = rb0;
    *reinterpret_cast<uint4*>(&Bs[srow * LDK + scol + 8]) = rb1;
    __syncthreads();
    if (kt + 1 < NN / BK) {
      const float* ap = aptr + (kt + 1) * BK;
      const unsigned short* bp = bptr + (kt + 1) * BK;
      ra0 = *reinterpret_cast<const float4*>(ap + 0);
      ra1 = *reinterpret_cast<const float4*>(ap + 4);
      ra2 = *reinterpret_cast<const float4*>(ap + 8);
      ra3 = *reinterpret_cast<const float4*>(ap + 12);
      rb0 = *reinterpret_cast<const uint4*>(bp + 0);
      rb1 = *reinterpret_cast<const uint4*>(bp + 8);
    }
    short8 af[4], bf[4];
#pragma unroll
    for (int tr = 0; tr < 4; ++tr)
      af[tr] = *reinterpret_cast<const short8*>(&As[(arow0 + tr * 16 + fr) * LDK + kb]);
#pragma unroll
    for (int tc = 0; tc < 4; ++tc)
      bf[tc] = *reinterpret_cast<const short8*>(&Bs[(brow0 + tc * 16 + fr) * LDK + kb]);
#pragma unroll
    for (int tr = 0; tr < 4; ++tr)
#pragma unroll
      for (int tc = 0; tc < 4; ++tc)
        acc[tr][tc] = __builtin_amdgcn_mfma_f32_16x16x32_bf16(af[tr], bf[tc], acc[tr][tc], 0, 0, 0);
  }

  const int rq = (lane >> 4) << 2;
#pragma unroll
  for (int tc = 0; tc < 4; ++tc) {
    const int gc = n0 + brow0 + tc * 16 + fr;
    const float bv = bias[gc];
#pragma unroll
    for (int tr = 0; tr < 4; ++tr) {
      const int gr = m0 + arow0 + tr * 16 + rq;
#pragma unroll
      for (int q = 0; q < 4; ++q) {
        Out[(size_t)(gr + q) * NN + gc] = acc[tr][tc][q] + bv;
      }
    }
  }
}

extern "C" void kernel_launch(void* const* d_in, const int* in_sizes, int n_in,
                              void* d_out, int out_size, void* d_ws, size_t ws_size,
                              hipStream_t stream) {
  const float* x = (const float*)d_in[0];
  const float* U = (const float*)d_in[1];
  const float* V = (const float*)d_in[2];
  const float* p = (const float*)d_in[3];
  const float* bias = (const float*)d_in[4];
  float* out = (float*)d_out;

  char* ws = (char*)d_ws;
  float* tau_u = (float*)(ws);
  float* tau_v = (float*)(ws + 4096);
  float* sigmas = (float*)(ws + 8192);
  float* T8all = (float*)(ws + 16384);              // 256*64*4 = 64 KB
  unsigned short* Mt = (unsigned short*)(ws + 81920);  // [1024][1024] bf16 = 2 MB

  prep_kernel<<<516, 256, 0, stream>>>(U, V, p, tau_u, tau_v, sigmas);
  gram_t8_kernel<<<256, 64, 0, stream>>>(U, V, tau_u, tau_v, T8all);
  build_m2_kernel<<<256, 256, 0, stream>>>(U, V, sigmas, T8all, Mt);
  gemm_kernel<<<1024, 256, 0, stream>>>(x, Mt, bias, out);
}

// Round 3
// 375.300 us; speedup vs baseline: 3.1382x; 1.4598x over previous
//
#include <hip/hip_runtime.h>
#include <stdint.h>

typedef __attribute__((ext_vector_type(8))) short short8;
typedef __attribute__((ext_vector_type(4))) float f32x4;

#define NN 1024
#define NBATCH 16384

__device__ __forceinline__ unsigned short f32_to_bf16_rne(float f) {
  unsigned int u = __float_as_uint(f);
  unsigned int r = (u + 0x7fffu + ((u >> 16) & 1u)) >> 16;
  return (unsigned short)r;
}

__device__ __forceinline__ unsigned int pack2bf(float lo, float hi) {
  return (unsigned int)f32_to_bf16_rne(lo) | ((unsigned int)f32_to_bf16_rne(hi) << 16);
}

// 64-lane all-reduce sum: 4 DPP (VALU) stages + ds_swizzle xor16 + shfl xor32.
__device__ __forceinline__ float allsum64(float x) {
  x += __int_as_float(__builtin_amdgcn_update_dpp(0, __float_as_int(x), 0xB1, 0xF, 0xF, true));   // quad_perm [1,0,3,2] : xor1
  x += __int_as_float(__builtin_amdgcn_update_dpp(0, __float_as_int(x), 0x4E, 0xF, 0xF, true));   // quad_perm [2,3,0,1] : xor2
  x += __int_as_float(__builtin_amdgcn_update_dpp(0, __float_as_int(x), 0x141, 0xF, 0xF, true));  // row_half_mirror : xor7
  x += __int_as_float(__builtin_amdgcn_update_dpp(0, __float_as_int(x), 0x140, 0xF, 0xF, true));  // row_mirror : xor15
  x += __int_as_float(__builtin_amdgcn_ds_swizzle(__float_as_int(x), 0x401F));                    // xor16 (within 32)
  x += __shfl_xor(x, 32);
  return x;
}

// -------------------- prep: tau = 2/(u.u), sigmas --------------------
__global__ __launch_bounds__(256) void prep_kernel(
    const float* __restrict__ U, const float* __restrict__ V,
    const float* __restrict__ p, float* __restrict__ tau_u,
    float* __restrict__ tau_v, float* __restrict__ sigmas) {
  int wave = threadIdx.x >> 6, lane = threadIdx.x & 63;
  int row = blockIdx.x * 4 + wave;
  if (row < 2048) {
    const float* u = (row < NN) ? (U + (size_t)row * NN) : (V + (size_t)(row - NN) * NN);
    float s = 0.f;
#pragma unroll
    for (int t = 0; t < 16; ++t) { float a = u[lane + (t << 6)]; s += a * a; }
    s = allsum64(s);
    if (lane == 0) {
      float tau = 2.0f / s;
      if (row < NN) tau_u[row] = tau;
      else tau_v[row - NN] = tau;
    }
  } else if (row < 2064) {
    int j = ((row - 2048) << 6) + lane;
    float pj = p[j];
    float sg = 1.0f / (1.0f + expf(-pj));
    sigmas[j] = 0.9f * (sg - 0.5f) + 0.55f;  // r=0.45, mean=0.55
  }
}

// -------------------- gram + T8 per block of 8 reflectors --------------------
// blk<128: U bank, rows 8*blk+j (j=0..7). blk>=128: s=blk-128, V bank, rows 1023-8s-j.
// T: T[j][j]=tau_j; T[i][j] = -tau_j * sum_{k=i..j-1} T[i][k]*G[k][j].
__global__ __launch_bounds__(64) void gram_t8_kernel(
    const float* __restrict__ U, const float* __restrict__ V,
    const float* __restrict__ tau_u, const float* __restrict__ tau_v,
    float* __restrict__ T8all) {
  __shared__ float G[64];
  const int blk = blockIdx.x;
  const int lane = threadIdx.x;
  const float* bank;
  int rbase, rsign, st;
  if (blk < 128) { bank = U; rbase = 8 * blk; rsign = 1; st = 8 * blk; }
  else { int s = blk - 128; bank = V; rbase = 1023 - 8 * s; rsign = -1; st = 1016 - 8 * s; }

  if (lane < 28) {
    int j = 1, k = 0, t = lane;
    for (int jj = 1; jj < 8; ++jj) {
      int lo = jj * (jj - 1) / 2, hi = jj * (jj + 1) / 2;
      if (t >= lo && t < hi) { j = jj; k = t - lo; }
    }
    const float* rk = bank + (size_t)(rbase + rsign * k) * NN;
    const float* rj = bank + (size_t)(rbase + rsign * j) * NN;
    float acc = 0.f;
    for (int i = st >> 2; i < 256; ++i) {
      float4 a = *reinterpret_cast<const float4*>(rk + 4 * i);
      float4 b = *reinterpret_cast<const float4*>(rj + 4 * i);
      acc += a.x * b.x + a.y * b.y + a.z * b.z + a.w * b.w;
    }
    G[k * 8 + j] = acc;
  }
  __syncthreads();

  if (lane < 8) {
    float Tr[8];
#pragma unroll
    for (int j = 0; j < 8; ++j) Tr[j] = 0.f;
#pragma unroll
    for (int j = 0; j < 8; ++j) {
      int grow = rbase + rsign * j;
      float tj = (blk < 128) ? tau_u[grow] : tau_v[grow];
      float a = 0.f;
#pragma unroll
      for (int k = 0; k < 8; ++k) {
        if (k < j) a += Tr[k] * G[k * 8 + j];
      }
      Tr[j] = (lane == j) ? tj : (-tj * a);
    }
#pragma unroll
    for (int j = 0; j < 8; ++j) T8all[(size_t)blk * 64 + lane * 8 + j] = Tr[j];
  }
}

// -------------------- build A and B rows (independent sides) --------------------
// side 0 (blocks 0..255): A = H_u0 ... H_u1023, then column-scale by sigma.
//   Store Aout[row][e] row-major bf16.
// side 1 (blocks 256..511): B = H_v1023 ... H_v0 (reverse order).
//   Store Bt[e][row] = B[row][e] (scatter) bf16.
// Element map: v[4q+r] holds e = 256q + 4*lane + r.
__device__ __forceinline__ void stage_block(int side, int step, float* lbuf, float* tbuf,
    const float* __restrict__ U, const float* __restrict__ V,
    const float* __restrict__ T8all, int wave, int lane) {
  if (step >= 128) return;
  int q0, rbase, rsign, t8i;
  const float* bank;
  if (side == 0) { q0 = step >> 5; bank = U; rbase = 8 * step; rsign = 1; t8i = step; }
  else { q0 = (1016 - 8 * step) >> 8; bank = V; rbase = 1023 - 8 * step; rsign = -1; t8i = 128 + step; }
#pragma unroll
  for (int c = 0; c < 8; ++c) {
    const int chunk = (wave << 3) + c;
    const int slot = chunk >> 2, q = chunk & 3;
    if (q < q0) continue;
    const int grow = rbase + rsign * slot;
    const float* gsrc = bank + (size_t)grow * NN + q * 256 + lane * 4;
    float* ldst = lbuf + slot * NN + q * 256;
    __builtin_amdgcn_global_load_lds(
        (const __attribute__((address_space(1))) void*)gsrc,
        (__attribute__((address_space(3))) void*)ldst, 16, 0, 0);
  }
  if (wave == 0 && lane < 16) {
    float4 t = *reinterpret_cast<const float4*>(T8all + (size_t)t8i * 64 + lane * 4);
    *reinterpret_cast<float4*>(tbuf + lane * 4) = t;
  }
}

template <int Q0>
__device__ __forceinline__ void apply_block(const float* __restrict__ ub,
    const float* __restrict__ tb, float* __restrict__ v, int lane) {
  float uc[8][(4 - Q0) * 4];
  float c[8];
#pragma unroll
  for (int j = 0; j < 8; ++j) {
    float acc = 0.f;
#pragma unroll
    for (int q = Q0; q < 4; ++q) {
      const float4 uu = *reinterpret_cast<const float4*>(&ub[j * NN + q * 256 + lane * 4]);
      const int ci = (q - Q0) * 4;
      uc[j][ci + 0] = uu.x; uc[j][ci + 1] = uu.y;
      uc[j][ci + 2] = uu.z; uc[j][ci + 3] = uu.w;
      acc += uu.x * v[4 * q + 0] + uu.y * v[4 * q + 1] +
             uu.z * v[4 * q + 2] + uu.w * v[4 * q + 3];
    }
    c[j] = acc;
  }
#pragma unroll
  for (int j = 0; j < 8; ++j) c[j] = allsum64(c[j]);
  float w[8];
#pragma unroll
  for (int j = 0; j < 8; ++j) {
    float acc = 0.f;
#pragma unroll
    for (int k = 0; k < 8; ++k) {
      if (k <= j) acc += c[k] * tb[k * 8 + j];
    }
    w[j] = acc;
  }
#pragma unroll
  for (int q = Q0; q < 4; ++q) {
#pragma unroll
    for (int r = 0; r < 4; ++r) {
      float acc = v[4 * q + r];
#pragma unroll
      for (int j = 0; j < 8; ++j) acc -= w[j] * uc[j][(q - Q0) * 4 + r];
      v[4 * q + r] = acc;
    }
  }
}

__global__ __launch_bounds__(256, 2) void build_ab_kernel(
    const float* __restrict__ U, const float* __restrict__ V,
    const float* __restrict__ sigmas, const float* __restrict__ T8all,
    unsigned short* __restrict__ Aout, unsigned short* __restrict__ Bt) {
  __shared__ float ubuf[2][8 * NN];
  __shared__ float tbuf[2][64];
  const int tid = threadIdx.x;
  const int wave = tid >> 6, lane = tid & 63;
  const int side = blockIdx.x >> 8;
  const int row = ((blockIdx.x & 255) << 2) + wave;

  float v[16];
#pragma unroll
  for (int q = 0; q < 4; ++q)
#pragma unroll
    for (int r = 0; r < 4; ++r)
      v[4 * q + r] = (256 * q + 4 * lane + r == row) ? 1.0f : 0.0f;

  stage_block(side, 0, ubuf[0], tbuf[0], U, V, T8all, wave, lane);
  int pb = 0;

#define SEG(Q0C, BASE)                                                          \
  for (int s = 0; s < 32; ++s) {                                                \
    const int step = (BASE) + s;                                                \
    __syncthreads(); /* staged buf landed (vmcnt drain), prev buf consumed */   \
    stage_block(side, step + 1, ubuf[pb ^ 1], tbuf[pb ^ 1], U, V, T8all, wave, lane); \
    apply_block<Q0C>(ubuf[pb], tbuf[pb], v, lane);                              \
    pb ^= 1;                                                                    \
  }

  if (side == 0) {
    SEG(0, 0) SEG(1, 32) SEG(2, 64) SEG(3, 96)
    // sigma column-scale, store A row-major (8B packed stores)
#pragma unroll
    for (int q = 0; q < 4; ++q) {
      float4 sg = *reinterpret_cast<const float4*>(&sigmas[256 * q + 4 * lane]);
      ushort4 pk;
      pk.x = f32_to_bf16_rne(v[4 * q + 0] * sg.x);
      pk.y = f32_to_bf16_rne(v[4 * q + 1] * sg.y);
      pk.z = f32_to_bf16_rne(v[4 * q + 2] * sg.z);
      pk.w = f32_to_bf16_rne(v[4 * q + 3] * sg.w);
      *reinterpret_cast<ushort4*>(&Aout[(size_t)row * NN + 256 * q + 4 * lane]) = pk;
    }
  } else {
    SEG(3, 0) SEG(2, 32) SEG(1, 64) SEG(0, 96)
    // store Bt[e][row] = B[row][e]
#pragma unroll
    for (int q = 0; q < 4; ++q)
#pragma unroll
      for (int r = 0; r < 4; ++r)
        Bt[(size_t)(256 * q + 4 * lane + r) * NN + row] = f32_to_bf16_rne(v[4 * q + r]);
  }
#undef SEG
}

// -------------------- compose: Mt[n][k] = sum_j Bt[n][j] * Aout[k][j] --------------------
#define BM 128
#define BN 128
#define BK 32
#define LDK 40

__global__ __launch_bounds__(256) void compose_kernel(
    const unsigned short* __restrict__ Xb, const unsigned short* __restrict__ Wb,
    unsigned short* __restrict__ Mt) {
  __shared__ unsigned short As[BM * LDK];
  __shared__ unsigned short Bs[BN * LDK];
  const int tid = threadIdx.x;
  const int lane = tid & 63, wave = tid >> 6;
  const int bm = blockIdx.x & 7;
  const int bn = blockIdx.x >> 3;
  const int m0 = bm * BM, n0 = bn * BN;
  const int wm = wave & 1, wn = wave >> 1;

  const int srow = tid >> 1;
  const int scol = (tid & 1) << 4;
  const unsigned short* aptr = Xb + (size_t)(m0 + srow) * NN + scol;
  const unsigned short* bptr = Wb + (size_t)(n0 + srow) * NN + scol;

  f32x4 acc[4][4];
#pragma unroll
  for (int a = 0; a < 4; ++a)
#pragma unroll
    for (int b = 0; b < 4; ++b) acc[a][b] = 0.f;

  uint4 ra0 = *reinterpret_cast<const uint4*>(aptr + 0);
  uint4 ra1 = *reinterpret_cast<const uint4*>(aptr + 8);
  uint4 rb0 = *reinterpret_cast<const uint4*>(bptr + 0);
  uint4 rb1 = *reinterpret_cast<const uint4*>(bptr + 8);

  const int arow0 = wm * 64;
  const int brow0 = wn * 64;
  const int fr = lane & 15;
  const int kb = (lane >> 4) << 3;

#pragma unroll 1
  for (int kt = 0; kt < NN / BK; ++kt) {
    __syncthreads();
    *reinterpret_cast<uint4*>(&As[srow * LDK + scol]) = ra0;
    *reinterpret_cast<uint4*>(&As[srow * LDK + scol + 8]) = ra1;
    *reinterpret_cast<uint4*>(&Bs[srow * LDK + scol]) = rb0;
    *reinterpret_cast<uint4*>(&Bs[srow * LDK + scol + 8]) = rb1;
    __syncthreads();
    if (kt + 1 < NN / BK) {
      const unsigned short* ap = aptr + (kt + 1) * BK;
      const unsigned short* bp = bptr + (kt + 1) * BK;
      ra0 = *reinterpret_cast<const uint4*>(ap + 0);
      ra1 = *reinterpret_cast<const uint4*>(ap + 8);
      rb0 = *reinterpret_cast<const uint4*>(bp + 0);
      rb1 = *reinterpret_cast<const uint4*>(bp + 8);
    }
    short8 af[4], bf[4];
#pragma unroll
    for (int tr = 0; tr < 4; ++tr)
      af[tr] = *reinterpret_cast<const short8*>(&As[(arow0 + tr * 16 + fr) * LDK + kb]);
#pragma unroll
    for (int tc = 0; tc < 4; ++tc)
      bf[tc] = *reinterpret_cast<const short8*>(&Bs[(brow0 + tc * 16 + fr) * LDK + kb]);
#pragma unroll
    for (int tr = 0; tr < 4; ++tr)
#pragma unroll
      for (int tc = 0; tc < 4; ++tc)
        acc[tr][tc] = __builtin_amdgcn_mfma_f32_16x16x32_bf16(af[tr], bf[tc], acc[tr][tc], 0, 0, 0);
  }

  const int rq = (lane >> 4) << 2;
#pragma unroll
  for (int tc = 0; tc < 4; ++tc) {
    const int gc = n0 + brow0 + tc * 16 + fr;
#pragma unroll
    for (int tr = 0; tr < 4; ++tr) {
      const int gr = m0 + arow0 + tr * 16 + rq;
#pragma unroll
      for (int q = 0; q < 4; ++q) {
        Mt[(size_t)(gr + q) * NN + gc] = f32_to_bf16_rne(acc[tr][tc][q]);
      }
    }
  }
}

// -------------------- GEMM: out = x @ M + bias (X f32 -> bf16 on the fly) ----
__global__ __launch_bounds__(256) void gemm_kernel(
    const float* __restrict__ X, const unsigned short* __restrict__ Mt,
    const float* __restrict__ bias, float* __restrict__ Out) {
  __shared__ unsigned short As[BM * LDK];
  __shared__ unsigned short Bs[BN * LDK];
  const int tid = threadIdx.x;
  const int lane = tid & 63, wave = tid >> 6;
  const int bm = blockIdx.x & 127;
  const int bn = blockIdx.x >> 7;
  const int m0 = bm * BM, n0 = bn * BN;
  const int wm = wave & 1, wn = wave >> 1;

  const int srow = tid >> 1;
  const int scol = (tid & 1) << 4;
  const float* aptr = X + (size_t)(m0 + srow) * NN + scol;
  const unsigned short* bptr = Mt + (size_t)(n0 + srow) * NN + scol;

  f32x4 acc[4][4];
#pragma unroll
  for (int a = 0; a < 4; ++a)
#pragma unroll
    for (int b = 0; b < 4; ++b) acc[a][b] = 0.f;

  float4 ra0 = *reinterpret_cast<const float4*>(aptr + 0);
  float4 ra1 = *reinterpret_cast<const float4*>(aptr + 4);
  float4 ra2 = *reinterpret_cast<const float4*>(aptr + 8);
  float4 ra3 = *reinterpret_cast<const float4*>(aptr + 12);
  uint4 rb0 = *reinterpret_cast<const uint4*>(bptr + 0);
  uint4 rb1 = *reinterpret_cast<const uint4*>(bptr + 8);

  const int arow0 = wm * 64;
  const int brow0 = wn * 64;
  const int fr = lane & 15;
  const int kb = (lane >> 4) << 3;

#pragma unroll 1
  for (int kt = 0; kt < NN / BK; ++kt) {
    __syncthreads();
    uint4 w0, w1;
    w0.x = pack2bf(ra0.x, ra0.y); w0.y = pack2bf(ra0.z, ra0.w);
    w0.z = pack2bf(ra1.x, ra1.y); w0.w = pack2bf(ra1.z, ra1.w);
    w1.x = pack2bf(ra2.x, ra2.y); w1.y = pack2bf(ra2.z, ra2.w);
    w1.z = pack2bf(ra3.x, ra3.y); w1.w = pack2bf(ra3.z, ra3.w);
    *reinterpret_cast<uint4*>(&As[srow * LDK + scol]) = w0;
    *reinterpret_cast<uint4*>(&As[srow * LDK + scol + 8]) = w1;
    *reinterpret_cast<uint4*>(&Bs[srow * LDK + scol]) = rb0;
    *reinterpret_cast<uint4*>(&Bs[srow * LDK + scol + 8]) = rb1;
    __syncthreads();
    if (kt + 1 < NN / BK) {
      const float* ap = aptr + (kt + 1) * BK;
      const unsigned short* bp = bptr + (kt + 1) * BK;
      ra0 = *reinterpret_cast<const float4*>(ap + 0);
      ra1 = *reinterpret_cast<const float4*>(ap + 4);
      ra2 = *reinterpret_cast<const float4*>(ap + 8);
      ra3 = *reinterpret_cast<const float4*>(ap + 12);
      rb0 = *reinterpret_cast<const uint4*>(bp + 0);
      rb1 = *reinterpret_cast<const uint4*>(bp + 8);
    }
    short8 af[4], bf[4];
#pragma unroll
    for (int tr = 0; tr < 4; ++tr)
      af[tr] = *reinterpret_cast<const short8*>(&As[(arow0 + tr * 16 + fr) * LDK + kb]);
#pragma unroll
    for (int tc = 0; tc < 4; ++tc)
      bf[tc] = *reinterpret_cast<const short8*>(&Bs[(brow0 + tc * 16 + fr) * LDK + kb]);
#pragma unroll
    for (int tr = 0; tr < 4; ++tr)
#pragma unroll
      for (int tc = 0; tc < 4; ++tc)
        acc[tr][tc] = __builtin_amdgcn_mfma_f32_16x16x32_bf16(af[tr], bf[tc], acc[tr][tc], 0, 0, 0);
  }

  const int rq = (lane >> 4) << 2;
#pragma unroll
  for (int tc = 0; tc < 4; ++tc) {
    const int gc = n0 + brow0 + tc * 16 + fr;
    const float bv = bias[gc];
#pragma unroll
    for (int tr = 0; tr < 4; ++tr) {
      const int gr = m0 + arow0 + tr * 16 + rq;
#pragma unroll
      for (int q = 0; q < 4; ++q) {
        Out[(size_t)(gr + q) * NN + gc] = acc[tr][tc][q] + bv;
      }
    }
  }
}

extern "C" void kernel_launch(void* const* d_in, const int* in_sizes, int n_in,
                              void* d_out, int out_size, void* d_ws, size_t ws_size,
                              hipStream_t stream) {
  const float* x = (const float*)d_in[0];
  const float* U = (const float*)d_in[1];
  const float* V = (const float*)d_in[2];
  const float* p = (const float*)d_in[3];
  const float* bias = (const float*)d_in[4];
  float* out = (float*)d_out;

  char* ws = (char*)d_ws;
  float* tau_u = (float*)(ws);
  float* tau_v = (float*)(ws + 4096);
  float* sigmas = (float*)(ws + 8192);
  float* T8all = (float*)(ws + 16384);                  // 64 KB
  unsigned short* Mt = (unsigned short*)(ws + 81920);   // 2 MB

  // A and B scratch live in d_out (64 MB); fully overwritten by gemm at the end.
  unsigned short* Aout = (unsigned short*)d_out;                       // 2 MB
  unsigned short* Bt = (unsigned short*)d_out + (size_t)NN * NN;       // 2 MB

  prep_kernel<<<516, 256, 0, stream>>>(U, V, p, tau_u, tau_v, sigmas);
  gram_t8_kernel<<<256, 64, 0, stream>>>(U, V, tau_u, tau_v, T8all);
  build_ab_kernel<<<512, 256, 0, stream>>>(U, V, sigmas, T8all, Aout, Bt);
  compose_kernel<<<64, 256, 0, stream>>>(Bt, Aout, Mt);
  gemm_kernel<<<1024, 256, 0, stream>>>(x, Mt, bias, out);
}